// Round 1
// baseline (517.377 us; speedup 1.0000x reference)
//
#include <hip/hip_runtime.h>
#include <hip/hip_bf16.h>

// Problem constants: B=4, C=64, F=256, T=256, CH=32
typedef __hip_bfloat16 bf16;
typedef __attribute__((ext_vector_type(8))) short bf16x8;
typedef __attribute__((ext_vector_type(4))) float f32x4;
typedef __attribute__((ext_vector_type(8))) unsigned short u16x8;

struct ConvP {
  const float* W; const float* bi; const float* g; const float* be;
  const float* m; const float* v; const float* a;
};

__device__ __forceinline__ unsigned short f2bf(float f) {
  __hip_bfloat16 h = __float2bfloat16(f);
  return __builtin_bit_cast(unsigned short, h);
}
__device__ __forceinline__ float bf2f(unsigned short u) {
  return __uint_as_float(((unsigned)u) << 16);
}

// ---------------------------------------------------------------------------
// Kernel A: fused 1x1 conv + BN + LeakyReLU for fqk (inp), tqk (inp), fv (x).
// Grid: 1024 = B*F blocks, 256 threads = T positions. Thread owns one (b,f,t)
// position; outputs de-interleaved (even ch -> Q, odd -> K) and stored bf16.
// Qf/Kf/Vf layout (B,T,F,CH); Qt/Kt layout (B,F,T,CH).
// ---------------------------------------------------------------------------
__global__ __launch_bounds__(256) void conv_qkv(
    const float* __restrict__ inp, const float* __restrict__ x,
    ConvP fqk, ConvP fv, ConvP tqk,
    bf16* __restrict__ Qf, bf16* __restrict__ Kf, bf16* __restrict__ Vf,
    bf16* __restrict__ Qt, bf16* __restrict__ Kt)
{
  const int tid = threadIdx.x;
  const int b = blockIdx.x >> 8;
  const int f = blockIdx.x & 255;

  const int inoff = b * 64 * 65536 + f * 256 + tid;   // (b,c=0,f,t)
  float in[64];
  #pragma unroll
  for (int c = 0; c < 64; ++c) in[c] = inp[inoff + c * 65536];

  const int rowF = ((b * 256 + tid) * 256 + f) * 32;  // (B,T,F,CH) row, t=tid
  const int rowT = ((b * 256 + f) * 256 + tid) * 32;  // (B,F,T,CH) row, t=tid

  #pragma unroll 1
  for (int which = 0; which < 2; ++which) {
    const ConvP& P = which ? tqk : fqk;
    bf16* Qa = which ? Qt : Qf;
    bf16* Ka = which ? Kt : Kf;
    const int row = which ? rowT : rowF;
    const float alpha = P.a[0];
    #pragma unroll 1
    for (int half = 0; half < 2; ++half) {
      const int c0 = half * 32;
      float acc[32];
      #pragma unroll
      for (int o = 0; o < 32; ++o) acc[o] = 0.f;
      const float* Wp = P.W + c0 * 64;
      #pragma unroll 4
      for (int i = 0; i < 64; ++i) {          // i-outer: W loads consecutive per o-row
        const float xi = in[i];
        #pragma unroll
        for (int o = 0; o < 32; ++o) acc[o] += Wp[o * 64 + i] * xi;
      }
      u16x8 qv0, qv1, kv0, kv1;
      #pragma unroll
      for (int o = 0; o < 32; ++o) {
        const int oc = c0 + o;
        const float s = rsqrtf(P.v[oc] + 1e-5f);
        const float A = P.g[oc] * s;
        float y = (acc[o] + P.bi[oc] - P.m[oc]) * A + P.be[oc];
        y = y > 0.f ? y : alpha * y;
        const unsigned short h = f2bf(y);
        const int ch = o >> 1;                // local channel within this half
        if ((o & 1) == 0) { if (ch < 8) qv0[ch] = h; else qv1[ch - 8] = h; }
        else              { if (ch < 8) kv0[ch] = h; else kv1[ch - 8] = h; }
      }
      const int chb = half * 16;
      *(u16x8*)(Qa + row + chb)     = qv0;
      *(u16x8*)(Qa + row + chb + 8) = qv1;
      *(u16x8*)(Ka + row + chb)     = kv0;
      *(u16x8*)(Ka + row + chb + 8) = kv1;
    }
  }
  // fv conv (input x, 32 outputs) -> Vf (B,T,F,CH)
  {
    #pragma unroll
    for (int c = 0; c < 64; ++c) in[c] = x[inoff + c * 65536];
    float acc[32];
    #pragma unroll
    for (int o = 0; o < 32; ++o) acc[o] = 0.f;
    #pragma unroll 4
    for (int i = 0; i < 64; ++i) {
      const float xi = in[i];
      #pragma unroll
      for (int o = 0; o < 32; ++o) acc[o] += fv.W[o * 64 + i] * xi;
    }
    const float alpha = fv.a[0];
    u16x8 vv[4];
    #pragma unroll
    for (int o = 0; o < 32; ++o) {
      const float s = rsqrtf(fv.v[o] + 1e-5f);
      const float A = fv.g[o] * s;
      float y = (acc[o] + fv.bi[o] - fv.m[o]) * A + fv.be[o];
      y = y > 0.f ? y : alpha * y;
      vv[o >> 3][o & 7] = f2bf(y);
    }
    #pragma unroll
    for (int q = 0; q < 4; ++q) *(u16x8*)(Vf + rowF + q * 8) = vv[q];
  }
}

// ---------------------------------------------------------------------------
// Attention kernel: 1024 instances of [256 rows x 256 cols, head dim 32].
// Q/K/V per-instance base = inst*8192, rows contiguous (row*32+c).
// Output element (row, c) at obase + row*orstride + c.
// 4 waves/WG; wave handles row-tiles rt = wid + 4*it. S accumulators in VGPR
// (16 x f32x4), softmax via width-16 shuffles, P through per-wave LDS buffer
// (D-layout -> A-layout), V transposed in LDS for contiguous PV B-frags.
// ---------------------------------------------------------------------------
template<bool CAUSAL>
__global__ __launch_bounds__(256) void attn_k(
    const bf16* __restrict__ Qg, const bf16* __restrict__ Kg,
    const bf16* __restrict__ Vg, bf16* __restrict__ Og)
{
  __shared__ __attribute__((aligned(16))) unsigned short Vt[32 * 264];       // V^T, pad to stride 264
  __shared__ __attribute__((aligned(16))) unsigned short Plds[4][16 * 264];  // per-wave P

  const int inst = blockIdx.x;
  const int b = inst >> 8;
  const int s = inst & 255;
  const int base = inst * 8192;
  const int obase = CAUSAL ? base : (b * (256 * 256 * 32) + s * 32);
  const int orstride = CAUSAL ? 32 : 8192;

  const int tid = threadIdx.x;
  // stage V transposed: thread j handles rows 2j, 2j+1 -> packed b32 writes
  if (tid < 128) {
    const unsigned short* v0 = (const unsigned short*)(Vg + base) + (2 * tid) * 32;
    const unsigned short* v1 = v0 + 32;
    u16x8 a[4], c[4];
    #pragma unroll
    for (int q = 0; q < 4; ++q) {
      a[q] = *(const u16x8*)(v0 + 8 * q);
      c[q] = *(const u16x8*)(v1 + 8 * q);
    }
    unsigned int* vt32 = (unsigned int*)Vt;
    #pragma unroll
    for (int cc = 0; cc < 32; ++cc) {
      unsigned lo = a[cc >> 3][cc & 7];
      unsigned hi = c[cc >> 3][cc & 7];
      vt32[(cc * 264 + 2 * tid) >> 1] = lo | (hi << 16);
    }
  }
  __syncthreads();

  const int lane = tid & 63;
  const int wid = tid >> 6;
  const int m16 = lane & 15;
  const int quad = lane >> 4;
  const float sc = 0.17677669529663687f;   // 1/sqrt(32)

  unsigned short* P = &Plds[wid][0];

  #pragma unroll 1
  for (int it = 0; it < 4; ++it) {
    const int rt = wid + 4 * it;
    const bf16x8 qf = *(const bf16x8*)(Qg + base + (rt * 16 + m16) * 32 + quad * 8);
    const int nct = CAUSAL ? (rt + 1) : 16;

    f32x4 acc[16];
    #pragma unroll
    for (int ct = 0; ct < 16; ++ct) {
      if (ct < nct) {
        const bf16x8 kf = *(const bf16x8*)(Kg + base + (ct * 16 + m16) * 32 + quad * 8);
        f32x4 z = {0.f, 0.f, 0.f, 0.f};
        acc[ct] = __builtin_amdgcn_mfma_f32_16x16x32_bf16(qf, kf, z, 0, 0, 0);
      }
    }
    // scale + causal mask + row max (D layout: col=lane&15, row=quad*4+reg)
    float mx[4] = {-3e38f, -3e38f, -3e38f, -3e38f};
    #pragma unroll
    for (int ct = 0; ct < 16; ++ct) if (ct < nct) {
      #pragma unroll
      for (int r = 0; r < 4; ++r) {
        float v = acc[ct][r] * sc;
        if (CAUSAL && (ct == nct - 1) && (m16 > quad * 4 + r)) v = -3e38f;
        acc[ct][r] = v;
        mx[r] = fmaxf(mx[r], v);
      }
    }
    #pragma unroll
    for (int r = 0; r < 4; ++r) {
      float m = mx[r];
      #pragma unroll
      for (int d = 1; d < 16; d <<= 1) m = fmaxf(m, __shfl_xor(m, d, 16));
      mx[r] = m;
    }
    float sum[4] = {0.f, 0.f, 0.f, 0.f};
    #pragma unroll
    for (int ct = 0; ct < 16; ++ct) if (ct < nct) {
      #pragma unroll
      for (int r = 0; r < 4; ++r) {
        float p = __expf(acc[ct][r] - mx[r]);
        acc[ct][r] = p;
        sum[r] += p;
      }
    }
    float inv[4];
    #pragma unroll
    for (int r = 0; r < 4; ++r) {
      float ssum = sum[r];
      #pragma unroll
      for (int d = 1; d < 16; d <<= 1) ssum += __shfl_xor(ssum, d, 16);
      inv[r] = 1.0f / ssum;
    }
    // write normalized P (bf16) to per-wave LDS
    #pragma unroll
    for (int ct = 0; ct < 16; ++ct) if (ct < nct) {
      #pragma unroll
      for (int r = 0; r < 4; ++r)
        P[(quad * 4 + r) * 264 + ct * 16 + m16] = f2bf(acc[ct][r] * inv[r]);
    }
    int ksteps = CAUSAL ? ((rt >> 1) + 1) : 8;
    if (CAUSAL && ((rt & 1) == 0)) {
      // zero-pad tile ct=rt+1 so the K=32 MFMA step covering it reads zeros
      #pragma unroll
      for (int u = 0; u < 4; ++u) {
        const int e = lane + 64 * u;
        P[(e >> 4) * 264 + (rt + 1) * 16 + (e & 15)] = 0;
      }
    }
    // O = P * V  (A-frag: m=lane&15, k=quad*8+j; B-frag from Vt rows)
    f32x4 o0 = {0.f, 0.f, 0.f, 0.f}, o1 = {0.f, 0.f, 0.f, 0.f};
    #pragma unroll
    for (int ks = 0; ks < 8; ++ks) {
      if (ks < ksteps) {
        const bf16x8 pf  = *(const bf16x8*)&P[m16 * 264 + ks * 32 + quad * 8];
        const bf16x8 vf0 = *(const bf16x8*)&Vt[m16 * 264 + ks * 32 + quad * 8];
        const bf16x8 vf1 = *(const bf16x8*)&Vt[(16 + m16) * 264 + ks * 32 + quad * 8];
        o0 = __builtin_amdgcn_mfma_f32_16x16x32_bf16(pf, vf0, o0, 0, 0, 0);
        o1 = __builtin_amdgcn_mfma_f32_16x16x32_bf16(pf, vf1, o1, 0, 0, 0);
      }
    }
    #pragma unroll
    for (int r = 0; r < 4; ++r) {
      const int row = rt * 16 + quad * 4 + r;
      Og[obase + row * orstride + m16]      = __float2bfloat16(o0[r]);
      Og[obase + row * orstride + 16 + m16] = __float2bfloat16(o1[r]);
    }
  }
}

// ---------------------------------------------------------------------------
// Kernel D: proj conv (32->64) + BN + LeakyReLU + residual add. fp32 output.
// ---------------------------------------------------------------------------
__global__ __launch_bounds__(256) void proj_k(
    const bf16* __restrict__ tout, const float* __restrict__ x,
    ConvP pj, float* __restrict__ out)
{
  const int tid = threadIdx.x;
  const int b = blockIdx.x >> 8;
  const int f = blockIdx.x & 255;
  const unsigned short* tp =
      (const unsigned short*)tout + ((b * 256 + f) * 256 + tid) * 32;
  u16x8 tv[4];
  #pragma unroll
  for (int q = 0; q < 4; ++q) tv[q] = *(const u16x8*)(tp + 8 * q);
  float vin[32];
  #pragma unroll
  for (int c = 0; c < 32; ++c) vin[c] = bf2f(tv[c >> 3][c & 7]);
  const float alpha = pj.a[0];
  const int xoff = b * 64 * 65536 + f * 256 + tid;
  #pragma unroll 4
  for (int o = 0; o < 64; ++o) {
    float acc = 0.f;
    #pragma unroll
    for (int i = 0; i < 32; ++i) acc += pj.W[o * 32 + i] * vin[i];
    const float s = rsqrtf(pj.v[o] + 1e-5f);
    const float A = pj.g[o] * s;
    float y = (acc + pj.bi[o] - pj.m[o]) * A + pj.be[o];
    y = y > 0.f ? y : alpha * y;
    out[xoff + o * 65536] = y + x[xoff + o * 65536];
  }
}

extern "C" void kernel_launch(void* const* d_in, const int* in_sizes, int n_in,
                              void* d_out, int out_size, void* d_ws, size_t ws_size,
                              hipStream_t stream) {
  const float* inp = (const float*)d_in[0];
  const float* x   = (const float*)d_in[1];
  auto cp = [&](int i) {
    return ConvP{ (const float*)d_in[i],     (const float*)d_in[i + 1],
                  (const float*)d_in[i + 2], (const float*)d_in[i + 3],
                  (const float*)d_in[i + 4], (const float*)d_in[i + 5],
                  (const float*)d_in[i + 6] };
  };
  ConvP fqk = cp(2), fv = cp(9), tqk = cp(16), pj = cp(23);

  char* ws = (char*)d_ws;
  const size_t SZ = (size_t)4 * 256 * 256 * 32 * 2;  // 16 MiB per bf16 buffer
  bf16* Qf = (bf16*)(ws + 0 * SZ);   // (B,T,F,CH)
  bf16* Kf = (bf16*)(ws + 1 * SZ);   // (B,T,F,CH)
  bf16* Vf = (bf16*)(ws + 2 * SZ);   // (B,T,F,CH)
  bf16* Qt = (bf16*)(ws + 3 * SZ);   // (B,F,T,CH)
  bf16* Kt = (bf16*)(ws + 4 * SZ);   // (B,F,T,CH)
  bf16* Ft = (bf16*)(ws + 5 * SZ);   // fout (B,F,T,CH)
  bf16* To = (bf16*)(ws + 0 * SZ);   // tout reuses Qf (dead after f-attn)

  conv_qkv<<<1024, 256, 0, stream>>>(inp, x, fqk, fv, tqk, Qf, Kf, Vf, Qt, Kt);
  attn_k<false><<<1024, 256, 0, stream>>>(Qf, Kf, Vf, Ft);   // freq attention
  attn_k<true><<<1024, 256, 0, stream>>>(Qt, Kt, Ft, To);    // causal time attention
  proj_k<<<1024, 256, 0, stream>>>(To, x, pj, (float*)d_out);
}